// Round 1
// baseline (751.008 us; speedup 1.0000x reference)
//
#include <hip/hip_runtime.h>

#define B_   8
#define N1_  2048
#define N2_  8192
#define C1_  256
#define C2_  128
#define KT_  384
#define O_   256

// ---------------- generic 32x32 tiled transpose: in[b][R][C] -> out[b][C][R] ----
__global__ __launch_bounds__(256) void k_transpose(const float* __restrict__ in,
                                                   float* __restrict__ out, int R, int C) {
  __shared__ float t[32][33];
  const int b = blockIdx.z;
  const float* pin = in + (size_t)b * R * C;
  float* pout = out + (size_t)b * R * C;
  const int c0 = blockIdx.x * 32, r0 = blockIdx.y * 32;
  const int tx = threadIdx.x, ty = threadIdx.y;
#pragma unroll
  for (int j = 0; j < 4; ++j)
    t[ty * 4 + j][tx] = pin[(size_t)(r0 + ty * 4 + j) * C + c0 + tx];
  __syncthreads();
#pragma unroll
  for (int j = 0; j < 4; ++j)
    pout[(size_t)(c0 + ty * 4 + j) * R + r0 + tx] = t[tx][ty * 4 + j];
}

// ---------------- three_nn + weights ----------------
__global__ __launch_bounds__(256) void k_three_nn(const float* __restrict__ xyz2,
                                                  const float* __restrict__ xyz1,
                                                  int* __restrict__ ind,
                                                  float* __restrict__ wgt) {
  __shared__ __align__(16) float xs[N1_];
  __shared__ __align__(16) float ys[N1_];
  __shared__ __align__(16) float zs[N1_];
  const int b = blockIdx.y;
  const float* p1 = xyz1 + (size_t)b * 3 * N1_;
  for (int i = threadIdx.x; i < N1_; i += 256) {
    xs[i] = p1[i];
    ys[i] = p1[N1_ + i];
    zs[i] = p1[2 * N1_ + i];
  }
  __syncthreads();
  const int n = blockIdx.x * 256 + threadIdx.x;
  const float px = xyz2[(size_t)b * 3 * N2_ + n];
  const float py = xyz2[(size_t)b * 3 * N2_ + N2_ + n];
  const float pz = xyz2[(size_t)b * 3 * N2_ + 2 * N2_ + n];
  float d0 = 3.4e38f, d1 = 3.4e38f, d2 = 3.4e38f;
  int i0 = 0, i1 = 0, i2 = 0;
  for (int c = 0; c < N1_; c += 4) {
    const float4 x4 = *(const float4*)&xs[c];
    const float4 y4 = *(const float4*)&ys[c];
    const float4 z4 = *(const float4*)&zs[c];
#define PROC(J, XX, YY, ZZ)                                                  \
    {                                                                        \
      float dx = (XX) - px, dy = (YY) - py, dz = (ZZ) - pz;                  \
      float d = fmaf(dx, dx, fmaf(dy, dy, dz * dz));                         \
      if (d < d2) {                                                          \
        if (d < d0)      { d2 = d1; i2 = i1; d1 = d0; i1 = i0; d0 = d; i0 = c + (J); } \
        else if (d < d1) { d2 = d1; i2 = i1; d1 = d;  i1 = c + (J); }        \
        else             { d2 = d;  i2 = c + (J); }                          \
      }                                                                      \
    }
    PROC(0, x4.x, y4.x, z4.x)
    PROC(1, x4.y, y4.y, z4.y)
    PROC(2, x4.z, y4.z, z4.z)
    PROC(3, x4.w, y4.w, z4.w)
#undef PROC
  }
  d0 = fmaxf(d0, 1e-10f); d1 = fmaxf(d1, 1e-10f); d2 = fmaxf(d2, 1e-10f);
  const float v0 = 1.0f / d0, v1 = 1.0f / d1, v2 = 1.0f / d2;
  const float rs = 1.0f / (v0 + v1 + v2);
  const size_t base = ((size_t)b * N2_ + n) * 3;
  ind[base + 0] = i0; ind[base + 1] = i1; ind[base + 2] = i2;
  wgt[base + 0] = v0 * rs; wgt[base + 1] = v1 * rs; wgt[base + 2] = v2 * rs;
}

// ---------------- GEMM1: y1[n][256] = W1 * [interp;feat2] + b1, + BN partials ----
__global__ __launch_bounds__(256, 2) void k_gemm1(
    const float* __restrict__ f1t, const float* __restrict__ feat2,
    const int* __restrict__ ind, const float* __restrict__ wgt,
    const float* __restrict__ W1t, const float* __restrict__ bias,
    float* __restrict__ y1, float* __restrict__ part) {
  __shared__ __align__(16) float As[16 * 132];
  __shared__ __align__(16) float Bs[16 * 260];
  __shared__ int   sI[128 * 3];
  __shared__ float sWt[128 * 3];

  const int tid = threadIdx.x;
  const int gn0 = blockIdx.x * 128;
  const int b = gn0 >> 13;
  const int nb = gn0 & (N2_ - 1);

  for (int i = tid; i < 384; i += 256) {
    sI[i]  = ind[(size_t)gn0 * 3 + i];
    sWt[i] = wgt[(size_t)gn0 * 3 + i];
  }

  float acc[8][16];
#pragma unroll
  for (int i = 0; i < 8; ++i)
#pragma unroll
    for (int j = 0; j < 16; ++j) acc[i][j] = 0.0f;

  const int tn = tid >> 4;        // 0..15, n0 = tn*8
  const int to = tid & 15;        // o fragments at to*4 + seg*64
  const int n0 = tn * 8;
  const int kq = tid & 3;         // interp staging: k-quad
  const int np = tid >> 2;        // 0..63
  const int nA = tid & 127;       // feat2 staging
  const int khA = tid >> 7;       // 0..1

  const float* f1b = f1t + (size_t)b * N1_ * C1_;

  for (int ch = 0; ch < 24; ++ch) {
    const int kbase = ch * 16;
    __syncthreads();
    {  // stage B from W1t[k][o]
      const int o4 = (tid & 63) * 4;
      int kk = tid >> 6;
#pragma unroll
      for (int r = 0; r < 4; ++r, kk += 4)
        *(float4*)&Bs[kk * 260 + o4] = *(const float4*)&W1t[(size_t)(kbase + kk) * O_ + o4];
    }
    if (kbase < C1_) {  // interp part of A
#pragma unroll
      for (int p = 0; p < 2; ++p) {
        const int n = p * 64 + np;
        const int j0 = sI[n * 3 + 0], j1 = sI[n * 3 + 1], j2 = sI[n * 3 + 2];
        const float w0 = sWt[n * 3 + 0], w1 = sWt[n * 3 + 1], w2 = sWt[n * 3 + 2];
        const float* bp = f1b + kbase + kq * 4;
        const float4 va = *(const float4*)&bp[(size_t)j0 * C1_];
        const float4 vb = *(const float4*)&bp[(size_t)j1 * C1_];
        const float4 vc = *(const float4*)&bp[(size_t)j2 * C1_];
        const int kr = kq * 4;
        As[(kr + 0) * 132 + n] = w0 * va.x + w1 * vb.x + w2 * vc.x;
        As[(kr + 1) * 132 + n] = w0 * va.y + w1 * vb.y + w2 * vc.y;
        As[(kr + 2) * 132 + n] = w0 * va.z + w1 * vb.z + w2 * vc.z;
        As[(kr + 3) * 132 + n] = w0 * va.w + w1 * vb.w + w2 * vc.w;
      }
    } else {  // feat2 part of A
      const float* f2b = feat2 + ((size_t)b * C2_ + (kbase - C1_)) * N2_ + nb + nA;
#pragma unroll
      for (int j = 0; j < 8; ++j) {
        const int kk = khA * 8 + j;
        As[kk * 132 + nA] = f2b[(size_t)kk * N2_];
      }
    }
    __syncthreads();
#pragma unroll
    for (int kk = 0; kk < 16; ++kk) {
      float a[8], bv[16];
      *(float4*)&a[0] = *(const float4*)&As[kk * 132 + n0];
      *(float4*)&a[4] = *(const float4*)&As[kk * 132 + n0 + 4];
#pragma unroll
      for (int s = 0; s < 4; ++s)
        *(float4*)&bv[s * 4] = *(const float4*)&Bs[kk * 260 + s * 64 + to * 4];
#pragma unroll
      for (int i = 0; i < 8; ++i)
#pragma unroll
        for (int j = 0; j < 16; ++j)
          acc[i][j] = fmaf(a[i], bv[j], acc[i][j]);
    }
  }

  float bs[16];
#pragma unroll
  for (int s = 0; s < 4; ++s)
    *(float4*)&bs[s * 4] = *(const float4*)&bias[s * 64 + to * 4];
#pragma unroll
  for (int i = 0; i < 8; ++i)
#pragma unroll
    for (int j = 0; j < 16; ++j) acc[i][j] += bs[j];

#pragma unroll
  for (int i = 0; i < 8; ++i) {
    float* row = y1 + (size_t)(gn0 + n0 + i) * O_;
#pragma unroll
    for (int s = 0; s < 4; ++s) {
      float4 v = { acc[i][s * 4 + 0], acc[i][s * 4 + 1], acc[i][s * 4 + 2], acc[i][s * 4 + 3] };
      *(float4*)&row[s * 64 + to * 4] = v;
    }
  }

  float sum[16], sqs[16];
#pragma unroll
  for (int j = 0; j < 16; ++j) {
    float s = 0.0f, q = 0.0f;
#pragma unroll
    for (int i = 0; i < 8; ++i) { s += acc[i][j]; q = fmaf(acc[i][j], acc[i][j], q); }
    sum[j] = s; sqs[j] = q;
  }
  float* red = Bs;
  __syncthreads();
#pragma unroll
  for (int j = 0; j < 16; ++j) {
    const int o = (j >> 2) * 64 + to * 4 + (j & 3);
    red[tn * 256 + o] = sum[j];
  }
  __syncthreads();
  if (tid < 256) {
    float s = 0.0f;
#pragma unroll
    for (int t = 0; t < 16; ++t) s += red[t * 256 + tid];
    part[(size_t)blockIdx.x * 512 + tid] = s;
  }
  __syncthreads();
#pragma unroll
  for (int j = 0; j < 16; ++j) {
    const int o = (j >> 2) * 64 + to * 4 + (j & 3);
    red[tn * 256 + o] = sqs[j];
  }
  __syncthreads();
  if (tid < 256) {
    float q = 0.0f;
#pragma unroll
    for (int t = 0; t < 16; ++t) q += red[t * 256 + tid];
    part[(size_t)blockIdx.x * 512 + 256 + tid] = q;
  }
}

// ---------------- reduce partials -> a,c coefficients ----------------
__global__ __launch_bounds__(1024) void k_reduce(const float* __restrict__ part, int nblk,
                                                 const float* __restrict__ g,
                                                 const float* __restrict__ be,
                                                 float* __restrict__ stats) {
  __shared__ float r0[1024];
  __shared__ float r1[1024];
  const int o = threadIdx.x & 255, q = threadIdx.x >> 8;
  float s = 0.0f, sq = 0.0f;
  for (int i = q; i < nblk; i += 4) {
    s  += part[(size_t)i * 512 + o];
    sq += part[(size_t)i * 512 + 256 + o];
  }
  r0[threadIdx.x] = s; r1[threadIdx.x] = sq;
  __syncthreads();
  if (threadIdx.x < 256) {
    s  = r0[o] + r0[256 + o] + r0[512 + o] + r0[768 + o];
    sq = r1[o] + r1[256 + o] + r1[512 + o] + r1[768 + o];
    const float mean = s * (1.0f / 65536.0f);
    float var = sq * (1.0f / 65536.0f) - mean * mean;
    var = fmaxf(var, 0.0f);
    const float inv = rsqrtf(var + 1e-3f);
    const float a = g[o] * inv;
    stats[o] = a;
    stats[256 + o] = fmaf(-mean, a, be[o]);
  }
}

// ---------------- GEMM2: out[b][o][n] = W2 * relu(bn(y1)) + b2, + BN partials ----
__global__ __launch_bounds__(256, 2) void k_gemm2(
    const float* __restrict__ y1, const float* __restrict__ W2t,
    const float* __restrict__ stats1, const float* __restrict__ bias,
    float* __restrict__ out, float* __restrict__ part) {
  __shared__ __align__(16) float As[16 * 132];
  __shared__ __align__(16) float Bs[16 * 260];

  const int tid = threadIdx.x;
  const int gn0 = blockIdx.x * 128;
  const int b = gn0 >> 13;
  const int nb = gn0 & (N2_ - 1);

  float acc[8][16];
#pragma unroll
  for (int i = 0; i < 8; ++i)
#pragma unroll
    for (int j = 0; j < 16; ++j) acc[i][j] = 0.0f;

  const int tn = tid >> 4, to = tid & 15, n0 = tn * 8;
  const int kq = tid & 3, np = tid >> 2;

  for (int ch = 0; ch < 16; ++ch) {
    const int kbase = ch * 16;
    __syncthreads();
    {
      const int o4 = (tid & 63) * 4;
      int kk = tid >> 6;
#pragma unroll
      for (int r = 0; r < 4; ++r, kk += 4)
        *(float4*)&Bs[kk * 260 + o4] = *(const float4*)&W2t[(size_t)(kbase + kk) * O_ + o4];
    }
#pragma unroll
    for (int p = 0; p < 2; ++p) {
      const int n = p * 64 + np;
      const int k = kbase + kq * 4;
      const float4 yv = *(const float4*)&y1[(size_t)(gn0 + n) * O_ + k];
      const float4 av = *(const float4*)&stats1[k];
      const float4 cv = *(const float4*)&stats1[256 + k];
      const int kr = kq * 4;
      As[(kr + 0) * 132 + n] = fmaxf(fmaf(yv.x, av.x, cv.x), 0.0f);
      As[(kr + 1) * 132 + n] = fmaxf(fmaf(yv.y, av.y, cv.y), 0.0f);
      As[(kr + 2) * 132 + n] = fmaxf(fmaf(yv.z, av.z, cv.z), 0.0f);
      As[(kr + 3) * 132 + n] = fmaxf(fmaf(yv.w, av.w, cv.w), 0.0f);
    }
    __syncthreads();
#pragma unroll
    for (int kk = 0; kk < 16; ++kk) {
      float a[8], bv[16];
      *(float4*)&a[0] = *(const float4*)&As[kk * 132 + n0];
      *(float4*)&a[4] = *(const float4*)&As[kk * 132 + n0 + 4];
#pragma unroll
      for (int s = 0; s < 4; ++s)
        *(float4*)&bv[s * 4] = *(const float4*)&Bs[kk * 260 + s * 64 + to * 4];
#pragma unroll
      for (int i = 0; i < 8; ++i)
#pragma unroll
        for (int j = 0; j < 16; ++j)
          acc[i][j] = fmaf(a[i], bv[j], acc[i][j]);
    }
  }

  float bs[16];
#pragma unroll
  for (int s = 0; s < 4; ++s)
    *(float4*)&bs[s * 4] = *(const float4*)&bias[s * 64 + to * 4];
#pragma unroll
  for (int i = 0; i < 8; ++i)
#pragma unroll
    for (int j = 0; j < 16; ++j) acc[i][j] += bs[j];

  // store pre-BN layer-2 output to d_out [b][o][n]
#pragma unroll
  for (int j = 0; j < 16; ++j) {
    const int o = (j >> 2) * 64 + to * 4 + (j & 3);
    float* row = out + ((size_t)b * O_ + o) * N2_ + nb + n0;
    float4 v0 = { acc[0][j], acc[1][j], acc[2][j], acc[3][j] };
    float4 v1 = { acc[4][j], acc[5][j], acc[6][j], acc[7][j] };
    *(float4*)&row[0] = v0;
    *(float4*)&row[4] = v1;
  }

  float sum[16], sqs[16];
#pragma unroll
  for (int j = 0; j < 16; ++j) {
    float s = 0.0f, q = 0.0f;
#pragma unroll
    for (int i = 0; i < 8; ++i) { s += acc[i][j]; q = fmaf(acc[i][j], acc[i][j], q); }
    sum[j] = s; sqs[j] = q;
  }
  float* red = Bs;
  __syncthreads();
#pragma unroll
  for (int j = 0; j < 16; ++j) {
    const int o = (j >> 2) * 64 + to * 4 + (j & 3);
    red[tn * 256 + o] = sum[j];
  }
  __syncthreads();
  if (tid < 256) {
    float s = 0.0f;
#pragma unroll
    for (int t = 0; t < 16; ++t) s += red[t * 256 + tid];
    part[(size_t)blockIdx.x * 512 + tid] = s;
  }
  __syncthreads();
#pragma unroll
  for (int j = 0; j < 16; ++j) {
    const int o = (j >> 2) * 64 + to * 4 + (j & 3);
    red[tn * 256 + o] = sqs[j];
  }
  __syncthreads();
  if (tid < 256) {
    float q = 0.0f;
#pragma unroll
    for (int t = 0; t < 16; ++t) q += red[t * 256 + tid];
    part[(size_t)blockIdx.x * 512 + 256 + tid] = q;
  }
}

// ---------------- final BN+ReLU in place on d_out ----------------
__global__ __launch_bounds__(256) void k_final(float* __restrict__ out,
                                               const float* __restrict__ stats2) {
  const size_t idx = (size_t)blockIdx.x * 256 + threadIdx.x;  // float4 index
  const int o = (int)((idx >> 11) & 255);
  const float a = stats2[o], c = stats2[256 + o];
  float4 v = *((float4*)out + idx);
  v.x = fmaxf(fmaf(v.x, a, c), 0.0f);
  v.y = fmaxf(fmaf(v.y, a, c), 0.0f);
  v.z = fmaxf(fmaf(v.z, a, c), 0.0f);
  v.w = fmaxf(fmaf(v.w, a, c), 0.0f);
  *((float4*)out + idx) = v;
}

extern "C" void kernel_launch(void* const* d_in, const int* in_sizes, int n_in,
                              void* d_out, int out_size, void* d_ws, size_t ws_size,
                              hipStream_t stream) {
  (void)in_sizes; (void)n_in; (void)out_size; (void)ws_size;
  const float* xyz2  = (const float*)d_in[0];
  const float* xyz1  = (const float*)d_in[1];
  const float* feat2 = (const float*)d_in[2];
  const float* feat1 = (const float*)d_in[3];
  const float* W1  = (const float*)d_in[4];
  const float* b1  = (const float*)d_in[5];
  const float* g1  = (const float*)d_in[6];
  const float* be1 = (const float*)d_in[7];
  const float* W2  = (const float*)d_in[8];
  const float* b2  = (const float*)d_in[9];
  const float* g2  = (const float*)d_in[10];
  const float* be2 = (const float*)d_in[11];
  float* out = (float*)d_out;

  char* ws = (char*)d_ws;
  int*   ind   = (int*)  (ws + 0);          //  786432 B
  float* wgt   = (float*)(ws + 786432);     //  786432 B
  float* f1t   = (float*)(ws + 1572864);    // 16.78 MB
  float* W1t   = (float*)(ws + 18350080);   //  384 KB
  float* W2t   = (float*)(ws + 18743296);   //  256 KB
  float* y1    = (float*)(ws + 19005440);   // 67.1 MB
  float* part1 = (float*)(ws + 86114304);   //  1 MB
  float* part2 = (float*)(ws + 87162880);   //  1 MB
  float* st1   = (float*)(ws + 88211456);   //  2 KB
  float* st2   = (float*)(ws + 88213504);   //  2 KB

  k_transpose<<<dim3(64, 8, 8), dim3(32, 8), 0, stream>>>(feat1, f1t, C1_, N1_);
  k_transpose<<<dim3(12, 8, 1), dim3(32, 8), 0, stream>>>(W1, W1t, O_, KT_);
  k_transpose<<<dim3(8, 8, 1),  dim3(32, 8), 0, stream>>>(W2, W2t, O_, O_);
  k_three_nn<<<dim3(32, 8), 256, 0, stream>>>(xyz2, xyz1, ind, wgt);
  k_gemm1<<<512, 256, 0, stream>>>(f1t, feat2, ind, wgt, W1t, b1, y1, part1);
  k_reduce<<<1, 1024, 0, stream>>>(part1, 512, g1, be1, st1);
  k_gemm2<<<512, 256, 0, stream>>>(y1, W2t, st1, b2, out, part2);
  k_reduce<<<1, 1024, 0, stream>>>(part2, 512, g2, be2, st2);
  k_final<<<16384, 256, 0, stream>>>(out, st2);
}

// Round 2
// 292.434 us; speedup vs baseline: 2.5681x; 2.5681x over previous
//
#include <hip/hip_runtime.h>
#include <stdint.h>

#define B_   8
#define N1_  2048
#define N2_  8192

typedef unsigned short ushort_t;
typedef __attribute__((ext_vector_type(8))) short short8;
typedef __attribute__((ext_vector_type(8))) unsigned short ushort8;
typedef __attribute__((ext_vector_type(4))) unsigned short ushort4v;
typedef __attribute__((ext_vector_type(4))) float f32x4;

__device__ __forceinline__ float b2f(unsigned short u) {
  union { unsigned int i; float f; } v;
  v.i = ((unsigned int)u) << 16;
  return v.f;
}
__device__ __forceinline__ unsigned short f2b(float f) {  // RNE bf16 round
  unsigned int x = __builtin_bit_cast(unsigned int, f);
  unsigned int r = x + 0x7FFFu + ((x >> 16) & 1u);
  return (unsigned short)(r >> 16);
}
__device__ __forceinline__ f32x4 mfma16(ushort8 a, ushort8 b, f32x4 c) {
  return __builtin_amdgcn_mfma_f32_16x16x32_bf16(
      __builtin_bit_cast(short8, a), __builtin_bit_cast(short8, b), c, 0, 0, 0);
}
__device__ __forceinline__ void gl_lds16(const void* gsrc, void* ldst) {
  __builtin_amdgcn_global_load_lds(
      (const __attribute__((address_space(1))) unsigned int*)(uintptr_t)gsrc,
      (__attribute__((address_space(3))) unsigned int*)(uint32_t)(uintptr_t)ldst,
      16, 0, 0);
}

// ---------------- three_nn + weights ----------------
__global__ __launch_bounds__(256) void k_three_nn(const float* __restrict__ xyz2,
                                                  const float* __restrict__ xyz1,
                                                  int* __restrict__ ind,
                                                  float* __restrict__ wgt) {
  __shared__ __align__(16) float xs[N1_];
  __shared__ __align__(16) float ys[N1_];
  __shared__ __align__(16) float zs[N1_];
  const int b = blockIdx.y;
  const float* p1 = xyz1 + (size_t)b * 3 * N1_;
  for (int i = threadIdx.x; i < N1_; i += 256) {
    xs[i] = p1[i];
    ys[i] = p1[N1_ + i];
    zs[i] = p1[2 * N1_ + i];
  }
  __syncthreads();
  const int n = blockIdx.x * 256 + threadIdx.x;
  const float px = xyz2[(size_t)b * 3 * N2_ + n];
  const float py = xyz2[(size_t)b * 3 * N2_ + N2_ + n];
  const float pz = xyz2[(size_t)b * 3 * N2_ + 2 * N2_ + n];
  float d0 = 3.4e38f, d1 = 3.4e38f, d2 = 3.4e38f;
  int i0 = 0, i1 = 0, i2 = 0;
  for (int c = 0; c < N1_; c += 4) {
    const float4 x4 = *(const float4*)&xs[c];
    const float4 y4 = *(const float4*)&ys[c];
    const float4 z4 = *(const float4*)&zs[c];
#define PROC(J, XX, YY, ZZ)                                                  \
    {                                                                        \
      float dx = (XX) - px, dy = (YY) - py, dz = (ZZ) - pz;                  \
      float d = fmaf(dx, dx, fmaf(dy, dy, dz * dz));                         \
      if (d < d2) {                                                          \
        if (d < d0)      { d2 = d1; i2 = i1; d1 = d0; i1 = i0; d0 = d; i0 = c + (J); } \
        else if (d < d1) { d2 = d1; i2 = i1; d1 = d;  i1 = c + (J); }        \
        else             { d2 = d;  i2 = c + (J); }                          \
      }                                                                      \
    }
    PROC(0, x4.x, y4.x, z4.x)
    PROC(1, x4.y, y4.y, z4.y)
    PROC(2, x4.z, y4.z, z4.z)
    PROC(3, x4.w, y4.w, z4.w)
#undef PROC
  }
  d0 = fmaxf(d0, 1e-10f); d1 = fmaxf(d1, 1e-10f); d2 = fmaxf(d2, 1e-10f);
  const float v0 = 1.0f / d0, v1 = 1.0f / d1, v2 = 1.0f / d2;
  const float rs = 1.0f / (v0 + v1 + v2);
  const size_t base = ((size_t)b * N2_ + n) * 3;
  ind[base + 0] = i0; ind[base + 1] = i1; ind[base + 2] = i2;
  wgt[base + 0] = v0 * rs; wgt[base + 1] = v1 * rs; wgt[base + 2] = v2 * rs;
}

// ------------- transpose + f32->bf16: in[b][R][C] -> out[(b*C+n)][R] -------------
__global__ __launch_bounds__(256) void k_tcvt(const float* __restrict__ in,
                                              ushort_t* __restrict__ out, int R, int C) {
  __shared__ float t[32][33];
  const int b = blockIdx.z;
  const float* pin = in + (size_t)b * R * C;
  ushort_t* pout = out + (size_t)b * R * C;
  const int c0 = blockIdx.x * 32, r0 = blockIdx.y * 32;
  const int tx = threadIdx.x, ty = threadIdx.y;
#pragma unroll
  for (int j = 0; j < 4; ++j)
    t[ty * 4 + j][tx] = pin[(size_t)(r0 + ty * 4 + j) * C + c0 + tx];
  __syncthreads();
#pragma unroll
  for (int j = 0; j < 4; ++j)
    pout[(size_t)(c0 + ty * 4 + j) * R + r0 + tx] = f2b(t[tx][ty * 4 + j]);
}

// ---------------- elementwise f32 -> bf16 ----------------
__global__ __launch_bounds__(256) void k_wcvt(const float* __restrict__ in,
                                              ushort_t* __restrict__ out, int n) {
  const int i = (blockIdx.x * 256 + threadIdx.x) * 4;
  if (i < n) {
    const float4 v = *(const float4*)&in[i];
    ushort4v o;
    o[0] = f2b(v.x); o[1] = f2b(v.y); o[2] = f2b(v.z); o[3] = f2b(v.w);
    *(ushort4v*)&out[i] = o;
  }
}

// ---------------- GEMM1: y1[m][256] = [interp;feat2] x W1^T, MFMA bf16 ----------------
__global__ __launch_bounds__(512, 2) void k_gemm1(
    const ushort_t* __restrict__ f1tb, const ushort_t* __restrict__ f2tb,
    const int* __restrict__ ind, const float* __restrict__ wgt,
    const ushort_t* __restrict__ Wb, ushort_t* __restrict__ y1,
    float* __restrict__ part) {
  __shared__ __align__(16) ushort_t As[2][128 * 72];
  __shared__ __align__(16) ushort_t Bs[2][256 * 64];
  __shared__ int   sI[384];
  __shared__ float sWt[384];
  __shared__ float sRedS[512];
  __shared__ float sRedQ[512];

  const int tid = threadIdx.x;
  const int gm0 = blockIdx.x * 128;
  const int b   = gm0 >> 13;
  const int lane = tid & 63, wv = tid >> 6;
  const int wm = wv >> 2, wn = wv & 3;
  const int la = lane & 15, qg = lane >> 4;
  const int m0 = wm * 64, o0 = wn * 64;

  for (int i = tid; i < 384; i += 512) {
    sI[i]  = ind[(size_t)gm0 * 3 + i];
    sWt[i] = wgt[(size_t)gm0 * 3 + i];
  }
  __syncthreads();

  const int ar = tid >> 3;   // row slot a (0..63); slot b = ar+64
  const int ac = tid & 7;    // 16B chunk within 64-wide k-slab
  const int rb = ar + 64;
  const int j0a = sI[ar*3+0], j1a = sI[ar*3+1], j2a = sI[ar*3+2];
  const float w0a = sWt[ar*3+0], w1a = sWt[ar*3+1], w2a = sWt[ar*3+2];
  const int j0b = sI[rb*3+0], j1b = sI[rb*3+1], j2b = sI[rb*3+2];
  const float w0b = sWt[rb*3+0], w1b_ = sWt[rb*3+1], w2b = sWt[rb*3+2];

  const ushort_t* f1base = f1tb + (size_t)b * N1_ * 256;

  f32x4 acc[4][4];
#pragma unroll
  for (int mi = 0; mi < 4; ++mi)
#pragma unroll
    for (int ni = 0; ni < 4; ++ni) acc[mi][ni] = 0.0f;

  ushort8 g0, g1, g2, g3, g4, g5;

  auto LOAD_A = [&](int ch) {
    const int kbase = ch * 64;
    if (kbase < 256) {
      const int ka = kbase + ac * 8;
      g0 = *(const ushort8*)&f1base[(size_t)j0a * 256 + ka];
      g1 = *(const ushort8*)&f1base[(size_t)j1a * 256 + ka];
      g2 = *(const ushort8*)&f1base[(size_t)j2a * 256 + ka];
      g3 = *(const ushort8*)&f1base[(size_t)j0b * 256 + ka];
      g4 = *(const ushort8*)&f1base[(size_t)j1b * 256 + ka];
      g5 = *(const ushort8*)&f1base[(size_t)j2b * 256 + ka];
    } else {
      const int ka = (kbase - 256) + ac * 8;
      g0 = *(const ushort8*)&f2tb[(size_t)(gm0 + ar) * 128 + ka];
      g3 = *(const ushort8*)&f2tb[(size_t)(gm0 + rb) * 128 + ka];
    }
  };
  auto PROC_A = [&](int ch, int dst) {
    const int kbase = ch * 64;
    if (kbase < 256) {
      ushort8 oa, ob;
#pragma unroll
      for (int j = 0; j < 8; ++j) {
        oa[j] = f2b(w0a * b2f(g0[j]) + w1a * b2f(g1[j]) + w2a * b2f(g2[j]));
        ob[j] = f2b(w0b * b2f(g3[j]) + w1b_ * b2f(g4[j]) + w2b * b2f(g5[j]));
      }
      *(ushort8*)&As[dst][ar * 72 + ac * 8] = oa;
      *(ushort8*)&As[dst][rb * 72 + ac * 8] = ob;
    } else {
      *(ushort8*)&As[dst][ar * 72 + ac * 8] = g0;
      *(ushort8*)&As[dst][rb * 72 + ac * 8] = g3;
    }
  };
  auto STAGE_B = [&](int ch, int dst) {
    const int kbase = ch * 64;
#pragma unroll
    for (int i = 0; i < 4; ++i) {
      const int fc = i * 512 + tid;
      const int row = fc >> 3, p = fc & 7;
      const int c = p ^ (row & 7);
      gl_lds16(&Wb[(size_t)row * 384 + kbase + c * 8],
               &Bs[dst][i * 4096 + wv * 512]);
    }
  };
  auto COMPUTE = [&](int src) {
#pragma unroll
    for (int ks = 0; ks < 2; ++ks) {
      ushort8 af[4], bfr[4];
#pragma unroll
      for (int mi = 0; mi < 4; ++mi)
        af[mi] = *(const ushort8*)&As[src][(m0 + mi * 16 + la) * 72 + (ks * 4 + qg) * 8];
#pragma unroll
      for (int ni = 0; ni < 4; ++ni) {
        const int ro = o0 + ni * 16 + la;
        bfr[ni] = *(const ushort8*)&Bs[src][ro * 64 + (((ks * 4 + qg) ^ (ro & 7))) * 8];
      }
#pragma unroll
      for (int mi = 0; mi < 4; ++mi)
#pragma unroll
        for (int ni = 0; ni < 4; ++ni)
          acc[mi][ni] = mfma16(af[mi], bfr[ni], acc[mi][ni]);
    }
  };

  LOAD_A(0); STAGE_B(0, 0); PROC_A(0, 0);
  __syncthreads();
  int buf = 0;
  for (int ch = 0; ch < 6; ++ch) {
    const int nxt = ch + 1;
    if (nxt < 6) { STAGE_B(nxt, buf ^ 1); LOAD_A(nxt); }
    COMPUTE(buf);
    if (nxt < 6) PROC_A(nxt, buf ^ 1);
    __syncthreads();
    buf ^= 1;
  }

  // epilogue: y1 bf16 store
#pragma unroll
  for (int mi = 0; mi < 4; ++mi)
#pragma unroll
    for (int ni = 0; ni < 4; ++ni) {
      const int oc = o0 + ni * 16 + la;
#pragma unroll
      for (int r = 0; r < 4; ++r) {
        const int m = gm0 + m0 + mi * 16 + qg * 4 + r;
        y1[(size_t)m * 256 + oc] = f2b(acc[mi][ni][r]);
      }
    }
  // BN partial sums
#pragma unroll
  for (int ni = 0; ni < 4; ++ni) {
    float s = 0.f, qq = 0.f;
#pragma unroll
    for (int mi = 0; mi < 4; ++mi)
#pragma unroll
      for (int r = 0; r < 4; ++r) {
        const float v = acc[mi][ni][r];
        s += v; qq = fmaf(v, v, qq);
      }
    s += __shfl_xor(s, 16); s += __shfl_xor(s, 32);
    qq += __shfl_xor(qq, 16); qq += __shfl_xor(qq, 32);
    if (lane < 16) {
      sRedS[wm * 256 + o0 + ni * 16 + lane] = s;
      sRedQ[wm * 256 + o0 + ni * 16 + lane] = qq;
    }
  }
  __syncthreads();
  if (tid < 256) {
    part[(size_t)blockIdx.x * 512 + tid] = sRedS[tid] + sRedS[256 + tid];
    part[(size_t)blockIdx.x * 512 + 256 + tid] = sRedQ[tid] + sRedQ[256 + tid];
  }
}

// ---------------- reduce partials -> a,c coefficients ----------------
__global__ __launch_bounds__(1024) void k_reduce(const float* __restrict__ part, int nblk,
                                                 const float* __restrict__ g,
                                                 const float* __restrict__ be,
                                                 float* __restrict__ stats) {
  __shared__ float r0[1024];
  __shared__ float r1[1024];
  const int o = threadIdx.x & 255, q = threadIdx.x >> 8;
  float s = 0.0f, sq = 0.0f;
  for (int i = q; i < nblk; i += 4) {
    s  += part[(size_t)i * 512 + o];
    sq += part[(size_t)i * 512 + 256 + o];
  }
  r0[threadIdx.x] = s; r1[threadIdx.x] = sq;
  __syncthreads();
  if (threadIdx.x < 256) {
    s  = r0[o] + r0[256 + o] + r0[512 + o] + r0[768 + o];
    sq = r1[o] + r1[256 + o] + r1[512 + o] + r1[768 + o];
    const float mean = s * (1.0f / 65536.0f);
    float var = sq * (1.0f / 65536.0f) - mean * mean;
    var = fmaxf(var, 0.0f);
    const float inv = rsqrtf(var + 1e-3f);
    const float a = g[o] * inv;
    stats[o] = a;
    stats[256 + o] = fmaf(-mean, a, be[o]);
  }
}

// ---------------- GEMM2: y2[m][256] = relu(bn(y1)) x W2^T (in-place over y1) -------
__global__ __launch_bounds__(512, 2) void k_gemm2(
    ushort_t* y1, const ushort_t* __restrict__ Wb,
    const float* __restrict__ st1, float* __restrict__ part) {
  __shared__ __align__(16) ushort_t As[2][128 * 72];
  __shared__ __align__(16) ushort_t Bs[2][256 * 64];
  __shared__ float sSt[512];
  __shared__ float sRedS[512];
  __shared__ float sRedQ[512];

  const int tid = threadIdx.x;
  const int gm0 = blockIdx.x * 128;
  const int lane = tid & 63, wv = tid >> 6;
  const int wm = wv >> 2, wn = wv & 3;
  const int la = lane & 15, qg = lane >> 4;
  const int m0 = wm * 64, o0 = wn * 64;

  sSt[tid < 512 ? tid : 0] = st1[tid < 512 ? tid : 0];
  __syncthreads();

  const int ar = tid >> 3;
  const int ac = tid & 7;
  const int rb = ar + 64;

  f32x4 acc[4][4];
#pragma unroll
  for (int mi = 0; mi < 4; ++mi)
#pragma unroll
    for (int ni = 0; ni < 4; ++ni) acc[mi][ni] = 0.0f;

  ushort8 g0, g3;

  auto LOAD_A = [&](int ch) {
    const int ka = ch * 64 + ac * 8;
    g0 = *(const ushort8*)&y1[(size_t)(gm0 + ar) * 256 + ka];
    g3 = *(const ushort8*)&y1[(size_t)(gm0 + rb) * 256 + ka];
  };
  auto PROC_A = [&](int ch, int dst) {
    const int k0 = ch * 64 + ac * 8;
    ushort8 oa, ob;
#pragma unroll
    for (int j = 0; j < 8; ++j) {
      const float a = sSt[k0 + j], c = sSt[256 + k0 + j];
      oa[j] = f2b(fmaxf(fmaf(b2f(g0[j]), a, c), 0.0f));
      ob[j] = f2b(fmaxf(fmaf(b2f(g3[j]), a, c), 0.0f));
    }
    *(ushort8*)&As[dst][ar * 72 + ac * 8] = oa;
    *(ushort8*)&As[dst][rb * 72 + ac * 8] = ob;
  };
  auto STAGE_B = [&](int ch, int dst) {
    const int kbase = ch * 64;
#pragma unroll
    for (int i = 0; i < 4; ++i) {
      const int fc = i * 512 + tid;
      const int row = fc >> 3, p = fc & 7;
      const int c = p ^ (row & 7);
      gl_lds16(&Wb[(size_t)row * 256 + kbase + c * 8],
               &Bs[dst][i * 4096 + wv * 512]);
    }
  };
  auto COMPUTE = [&](int src) {
#pragma unroll
    for (int ks = 0; ks < 2; ++ks) {
      ushort8 af[4], bfr[4];
#pragma unroll
      for (int mi = 0; mi < 4; ++mi)
        af[mi] = *(const ushort8*)&As[src][(m0 + mi * 16 + la) * 72 + (ks * 4 + qg) * 8];
#pragma unroll
      for (int ni = 0; ni < 4; ++ni) {
        const int ro = o0 + ni * 16 + la;
        bfr[ni] = *(const ushort8*)&Bs[src][ro * 64 + (((ks * 4 + qg) ^ (ro & 7))) * 8];
      }
#pragma unroll
      for (int mi = 0; mi < 4; ++mi)
#pragma unroll
        for (int ni = 0; ni < 4; ++ni)
          acc[mi][ni] = mfma16(af[mi], bfr[ni], acc[mi][ni]);
    }
  };

  LOAD_A(0); STAGE_B(0, 0); PROC_A(0, 0);
  __syncthreads();
  int buf = 0;
  for (int ch = 0; ch < 4; ++ch) {
    const int nxt = ch + 1;
    if (nxt < 4) { STAGE_B(nxt, buf ^ 1); LOAD_A(nxt); }
    COMPUTE(buf);
    if (nxt < 4) PROC_A(nxt, buf ^ 1);
    __syncthreads();
    buf ^= 1;
  }

  // epilogue: y2 bf16 (pre-BN) in-place + partials
#pragma unroll
  for (int mi = 0; mi < 4; ++mi)
#pragma unroll
    for (int ni = 0; ni < 4; ++ni) {
      const int oc = o0 + ni * 16 + la;
#pragma unroll
      for (int r = 0; r < 4; ++r) {
        const int m = gm0 + m0 + mi * 16 + qg * 4 + r;
        y1[(size_t)m * 256 + oc] = f2b(acc[mi][ni][r]);
      }
    }
#pragma unroll
  for (int ni = 0; ni < 4; ++ni) {
    float s = 0.f, qq = 0.f;
#pragma unroll
    for (int mi = 0; mi < 4; ++mi)
#pragma unroll
      for (int r = 0; r < 4; ++r) {
        const float v = acc[mi][ni][r];
        s += v; qq = fmaf(v, v, qq);
      }
    s += __shfl_xor(s, 16); s += __shfl_xor(s, 32);
    qq += __shfl_xor(qq, 16); qq += __shfl_xor(qq, 32);
    if (lane < 16) {
      sRedS[wm * 256 + o0 + ni * 16 + lane] = s;
      sRedQ[wm * 256 + o0 + ni * 16 + lane] = qq;
    }
  }
  __syncthreads();
  if (tid < 256) {
    part[(size_t)blockIdx.x * 512 + tid] = sRedS[tid] + sRedS[256 + tid];
    part[(size_t)blockIdx.x * 512 + 256 + tid] = sRedQ[tid] + sRedQ[256 + tid];
  }
}

// ---------------- final: BN+ReLU + transpose y2[m][o] -> out[b][o][n] (f32) --------
__global__ __launch_bounds__(256) void k_final(const ushort_t* __restrict__ y2,
                                               const float* __restrict__ st2,
                                               float* __restrict__ out) {
  __shared__ __align__(16) ushort_t tile[64 * 264];
  const int t = threadIdx.x;
  const int n0 = blockIdx.x * 64;
  const int b = blockIdx.y;
#pragma unroll
  for (int r = 0; r < 8; ++r) {
    const int id = r * 256 + t;
    const int row = id >> 5, c8 = id & 31;
    *(ushort8*)&tile[row * 264 + c8 * 8] =
        *(const ushort8*)&y2[((size_t)b * N2_ + n0 + row) * 256 + c8 * 8];
  }
  __syncthreads();
#pragma unroll
  for (int r = 0; r < 16; ++r) {
    const int id = r * 256 + t;
    const int o = id >> 4, nq = id & 15;
    const float a = st2[o], c = st2[256 + o];
    float4 v;
    v.x = fmaxf(fmaf(b2f(tile[(nq * 4 + 0) * 264 + o]), a, c), 0.0f);
    v.y = fmaxf(fmaf(b2f(tile[(nq * 4 + 1) * 264 + o]), a, c), 0.0f);
    v.z = fmaxf(fmaf(b2f(tile[(nq * 4 + 2) * 264 + o]), a, c), 0.0f);
    v.w = fmaxf(fmaf(b2f(tile[(nq * 4 + 3) * 264 + o]), a, c), 0.0f);
    *(float4*)&out[((size_t)b * 256 + o) * N2_ + n0 + nq * 4] = v;
  }
}

extern "C" void kernel_launch(void* const* d_in, const int* in_sizes, int n_in,
                              void* d_out, int out_size, void* d_ws, size_t ws_size,
                              hipStream_t stream) {
  (void)in_sizes; (void)n_in; (void)out_size; (void)ws_size;
  const float* xyz2  = (const float*)d_in[0];
  const float* xyz1  = (const float*)d_in[1];
  const float* feat2 = (const float*)d_in[2];
  const float* feat1 = (const float*)d_in[3];
  const float* W1  = (const float*)d_in[4];
  const float* g1  = (const float*)d_in[6];
  const float* be1 = (const float*)d_in[7];
  const float* W2  = (const float*)d_in[8];
  const float* g2  = (const float*)d_in[10];
  const float* be2 = (const float*)d_in[11];
  float* out = (float*)d_out;

  char* ws = (char*)d_ws;
  int*      ind   = (int*)(ws);                    //   786,432
  float*    wgt   = (float*)(ws + 786432);         //   786,432
  ushort_t* f1tb  = (ushort_t*)(ws + 1572864);     // 8,388,608
  ushort_t* f2tb  = (ushort_t*)(ws + 9961472);     // 16,777,216
  ushort_t* W1b   = (ushort_t*)(ws + 26738688);    //   196,608
  ushort_t* W2b   = (ushort_t*)(ws + 26935296);    //   131,072
  float*    part1 = (float*)(ws + 27066368);       // 1,048,576
  float*    part2 = (float*)(ws + 28114944);       // 1,048,576
  float*    st1   = (float*)(ws + 29163520);       //     2,048
  float*    st2   = (float*)(ws + 29165568);       //     2,048
  ushort_t* y1    = (ushort_t*)(ws + 29167616);    // 33,554,432 (y2 in-place)

  k_three_nn<<<dim3(32, 8), 256, 0, stream>>>(xyz2, xyz1, ind, wgt);
  k_tcvt<<<dim3(64, 8, 8),  dim3(32, 8), 0, stream>>>(feat1, f1tb, 256, 2048);
  k_tcvt<<<dim3(256, 4, 8), dim3(32, 8), 0, stream>>>(feat2, f2tb, 128, 8192);
  k_wcvt<<<96, 256, 0, stream>>>(W1, W1b, 98304);
  k_wcvt<<<64, 256, 0, stream>>>(W2, W2b, 65536);
  k_gemm1<<<512, 512, 0, stream>>>(f1tb, f2tb, ind, wgt, W1b, y1, part1);
  k_reduce<<<1, 1024, 0, stream>>>(part1, 512, g1, be1, st1);
  k_gemm2<<<512, 512, 0, stream>>>(y1, W2b, st1, part2);
  k_reduce<<<1, 1024, 0, stream>>>(part2, 512, g2, be2, st2);
  k_final<<<dim3(128, 8), 256, 0, stream>>>(y1, st2, out);
}

// Round 4
// 220.414 us; speedup vs baseline: 3.4073x; 1.3268x over previous
//
#include <hip/hip_runtime.h>
#include <stdint.h>

#define B_   8
#define N1_  2048
#define N2_  8192

typedef unsigned short ushort_t;
typedef __attribute__((ext_vector_type(8))) short short8;
typedef __attribute__((ext_vector_type(8))) unsigned short ushort8;
typedef __attribute__((ext_vector_type(4))) unsigned short ushort4v;
typedef __attribute__((ext_vector_type(4))) float f32x4;

__device__ __forceinline__ float b2f(unsigned short u) {
  union { unsigned int i; float f; } v;
  v.i = ((unsigned int)u) << 16;
  return v.f;
}
__device__ __forceinline__ unsigned short f2b(float f) {  // RNE bf16 round
  unsigned int x = __builtin_bit_cast(unsigned int, f);
  unsigned int r = x + 0x7FFFu + ((x >> 16) & 1u);
  return (unsigned short)(r >> 16);
}
__device__ __forceinline__ f32x4 mfma16(ushort8 a, ushort8 b, f32x4 c) {
  return __builtin_amdgcn_mfma_f32_16x16x32_bf16(
      __builtin_bit_cast(short8, a), __builtin_bit_cast(short8, b), c, 0, 0, 0);
}
__device__ __forceinline__ void gl_lds16(const void* gsrc, void* ldst) {
  __builtin_amdgcn_global_load_lds(
      (const __attribute__((address_space(1))) unsigned int*)(uintptr_t)gsrc,
      (__attribute__((address_space(3))) unsigned int*)(uint32_t)(uintptr_t)ldst,
      16, 0, 0);
}

// ------- three_nn: 4 threads/query, exact-f32 branchless (d,i) top-3 network -------
__global__ __launch_bounds__(256) void k_three_nn(const float* __restrict__ xyz2,
                                                  const float* __restrict__ xyz1,
                                                  int* __restrict__ ind,
                                                  float* __restrict__ wgt) {
  // chunk-padded [3][4][520]: the 4 chunk base addresses hit disjoint banks
  __shared__ __align__(16) float sm[3][2080];
  const int b = blockIdx.y;
  const float* p1 = xyz1 + (size_t)b * 3 * N1_;
  for (int i = threadIdx.x; i < N1_; i += 256) {
    const int a = (i >> 9) * 520 + (i & 511);
    sm[0][a] = p1[i];
    sm[1][a] = p1[N1_ + i];
    sm[2][a] = p1[2 * N1_ + i];
  }
  __syncthreads();

  const int q = threadIdx.x >> 2, c = threadIdx.x & 3;
  const int n = blockIdx.x * 64 + q;
  const float px = xyz2[(size_t)b * 3 * N2_ + n];
  const float py = xyz2[(size_t)b * 3 * N2_ + N2_ + n];
  const float pz = xyz2[(size_t)b * 3 * N2_ + 2 * N2_ + n];

  float dk0 = 3.4e38f, dk1 = 3.4e38f, dk2 = 3.4e38f;
  int   ik0 = 0, ik1 = 0, ik2 = 0;
  const float* mx = &sm[0][c * 520];
  const float* my = &sm[1][c * 520];
  const float* mz = &sm[2][c * 520];

  // branchless insert of (DD,II); strict < keeps earlier index on ties (top_k rule)
#define INS(DD, II)                                                      \
  {                                                                      \
    const bool c2_ = (DD) < dk2;                                         \
    dk2 = c2_ ? (DD) : dk2; ik2 = c2_ ? (II) : ik2;                      \
    const bool c1_ = dk2 < dk1;                                          \
    float tf_ = c1_ ? dk2 : dk1; dk2 = c1_ ? dk1 : dk2; dk1 = tf_;       \
    int   ti_ = c1_ ? ik2 : ik1; ik2 = c1_ ? ik1 : ik2; ik1 = ti_;       \
    const bool c0_ = dk1 < dk0;                                          \
    tf_ = c0_ ? dk1 : dk0; dk1 = c0_ ? dk0 : dk1; dk0 = tf_;             \
    ti_ = c0_ ? ik1 : ik0; ik1 = c0_ ? ik0 : ik1; ik0 = ti_;             \
  }

  int idx = c * 512;
  for (int i = 0; i < 512; i += 4, idx += 4) {
    const float4 x4 = *(const float4*)(mx + i);
    const float4 y4 = *(const float4*)(my + i);
    const float4 z4 = *(const float4*)(mz + i);
#define CAND(J, XX, YY, ZZ)                                  \
    {                                                        \
      const float dx = (XX) - px;                            \
      const float dy = (YY) - py;                            \
      const float dz = (ZZ) - pz;                            \
      const float d = fmaf(dx, dx, fmaf(dy, dy, dz * dz));   \
      INS(d, idx + (J))                                      \
    }
    CAND(0, x4.x, y4.x, z4.x)
    CAND(1, x4.y, y4.y, z4.y)
    CAND(2, x4.z, y4.z, z4.z)
    CAND(3, x4.w, y4.w, z4.w)
#undef CAND
  }

  // merge partial top-3 across the 4 chunk lanes; lower chunk (lower idx) wins ties
#pragma unroll
  for (int d = 1; d <= 2; d <<= 1) {
    const float r0 = __shfl_xor(dk0, d);
    const float r1 = __shfl_xor(dk1, d);
    const float r2 = __shfl_xor(dk2, d);
    const int   s0 = __shfl_xor(ik0, d);
    const int   s1 = __shfl_xor(ik1, d);
    const int   s2 = __shfl_xor(ik2, d);
    INS(r0, s0) INS(r1, s1) INS(r2, s2)
  }
#undef INS

  if (c == 0) {
    const float d0 = fmaxf(dk0, 1e-10f);
    const float d1 = fmaxf(dk1, 1e-10f);
    const float d2 = fmaxf(dk2, 1e-10f);
    const float v0 = 1.0f / d0, v1 = 1.0f / d1, v2 = 1.0f / d2;
    const float rs = 1.0f / (v0 + v1 + v2);
    const size_t base = ((size_t)b * N2_ + n) * 3;
    ind[base + 0] = ik0; ind[base + 1] = ik1; ind[base + 2] = ik2;
    wgt[base + 0] = v0 * rs; wgt[base + 1] = v1 * rs; wgt[base + 2] = v2 * rs;
  }
}

// ------------- transpose + f32->bf16: in[b][R][C] -> out[(b*C+n)][R] -------------
__global__ __launch_bounds__(256) void k_tcvt(const float* __restrict__ in,
                                              ushort_t* __restrict__ out, int R, int C) {
  __shared__ float t[32][33];
  const int b = blockIdx.z;
  const float* pin = in + (size_t)b * R * C;
  ushort_t* pout = out + (size_t)b * R * C;
  const int c0 = blockIdx.x * 32, r0 = blockIdx.y * 32;
  const int tx = threadIdx.x, ty = threadIdx.y;
#pragma unroll
  for (int j = 0; j < 4; ++j)
    t[ty * 4 + j][tx] = pin[(size_t)(r0 + ty * 4 + j) * C + c0 + tx];
  __syncthreads();
#pragma unroll
  for (int j = 0; j < 4; ++j)
    pout[(size_t)(c0 + ty * 4 + j) * R + r0 + tx] = f2b(t[tx][ty * 4 + j]);
}

// ---------------- elementwise f32 -> bf16 ----------------
__global__ __launch_bounds__(256) void k_wcvt(const float* __restrict__ in,
                                              ushort_t* __restrict__ out, int n) {
  const int i = (blockIdx.x * 256 + threadIdx.x) * 4;
  if (i < n) {
    const float4 v = *(const float4*)&in[i];
    ushort4v o;
    o[0] = f2b(v.x); o[1] = f2b(v.y); o[2] = f2b(v.z); o[3] = f2b(v.w);
    *(ushort4v*)&out[i] = o;
  }
}

// ---------------- GEMM1: y1[m][256] = [interp;feat2] x W1^T, MFMA bf16 ----------------
__global__ __launch_bounds__(512, 2) void k_gemm1(
    const ushort_t* __restrict__ f1tb, const ushort_t* __restrict__ f2tb,
    const int* __restrict__ ind, const float* __restrict__ wgt,
    const ushort_t* __restrict__ Wb, ushort_t* __restrict__ y1,
    float* __restrict__ part) {
  __shared__ __align__(16) ushort_t As[2][128 * 72];
  __shared__ __align__(16) ushort_t Bs[2][256 * 64];
  __shared__ int   sI[384];
  __shared__ float sWt[384];
  __shared__ float sRedS[512];
  __shared__ float sRedQ[512];

  const int tid = threadIdx.x;
  const int gm0 = blockIdx.x * 128;
  const int b   = gm0 >> 13;
  const int lane = tid & 63, wv = tid >> 6;
  const int wm = wv >> 2, wn = wv & 3;
  const int la = lane & 15, qg = lane >> 4;
  const int m0 = wm * 64, o0 = wn * 64;

  for (int i = tid; i < 384; i += 512) {
    sI[i]  = ind[(size_t)gm0 * 3 + i];
    sWt[i] = wgt[(size_t)gm0 * 3 + i];
  }
  __syncthreads();

  const int ar = tid >> 3;   // row slot a (0..63); slot b = ar+64
  const int ac = tid & 7;    // 16B chunk within 64-wide k-slab
  const int rb = ar + 64;
  const int j0a = sI[ar*3+0], j1a = sI[ar*3+1], j2a = sI[ar*3+2];
  const float w0a = sWt[ar*3+0], w1a = sWt[ar*3+1], w2a = sWt[ar*3+2];
  const int j0b = sI[rb*3+0], j1b = sI[rb*3+1], j2b = sI[rb*3+2];
  const float w0b = sWt[rb*3+0], w1b_ = sWt[rb*3+1], w2b = sWt[rb*3+2];

  const ushort_t* f1base = f1tb + (size_t)b * N1_ * 256;

  f32x4 acc[4][4];
#pragma unroll
  for (int mi = 0; mi < 4; ++mi)
#pragma unroll
    for (int ni = 0; ni < 4; ++ni) acc[mi][ni] = 0.0f;

  ushort8 g0, g1, g2, g3, g4, g5;

  auto LOAD_A = [&](int ch) {
    const int kbase = ch * 64;
    if (kbase < 256) {
      const int ka = kbase + ac * 8;
      g0 = *(const ushort8*)&f1base[(size_t)j0a * 256 + ka];
      g1 = *(const ushort8*)&f1base[(size_t)j1a * 256 + ka];
      g2 = *(const ushort8*)&f1base[(size_t)j2a * 256 + ka];
      g3 = *(const ushort8*)&f1base[(size_t)j0b * 256 + ka];
      g4 = *(const ushort8*)&f1base[(size_t)j1b * 256 + ka];
      g5 = *(const ushort8*)&f1base[(size_t)j2b * 256 + ka];
    } else {
      const int ka = (kbase - 256) + ac * 8;
      g0 = *(const ushort8*)&f2tb[(size_t)(gm0 + ar) * 128 + ka];
      g3 = *(const ushort8*)&f2tb[(size_t)(gm0 + rb) * 128 + ka];
    }
  };
  auto PROC_A = [&](int ch, int dst) {
    const int kbase = ch * 64;
    if (kbase < 256) {
      ushort8 oa, ob;
#pragma unroll
      for (int j = 0; j < 8; ++j) {
        oa[j] = f2b(w0a * b2f(g0[j]) + w1a * b2f(g1[j]) + w2a * b2f(g2[j]));
        ob[j] = f2b(w0b * b2f(g3[j]) + w1b_ * b2f(g4[j]) + w2b * b2f(g5[j]));
      }
      *(ushort8*)&As[dst][ar * 72 + ac * 8] = oa;
      *(ushort8*)&As[dst][rb * 72 + ac * 8] = ob;
    } else {
      *(ushort8*)&As[dst][ar * 72 + ac * 8] = g0;
      *(ushort8*)&As[dst][rb * 72 + ac * 8] = g3;
    }
  };
  auto STAGE_B = [&](int ch, int dst) {
    const int kbase = ch * 64;
#pragma unroll
    for (int i = 0; i < 4; ++i) {
      const int fc = i * 512 + tid;
      const int row = fc >> 3, p = fc & 7;
      const int c = p ^ (row & 7);
      gl_lds16(&Wb[(size_t)row * 384 + kbase + c * 8],
               &Bs[dst][i * 4096 + wv * 512]);
    }
  };
  auto COMPUTE = [&](int src) {
#pragma unroll
    for (int ks = 0; ks < 2; ++ks) {
      ushort8 af[4], bfr[4];
#pragma unroll
      for (int mi = 0; mi < 4; ++mi)
        af[mi] = *(const ushort8*)&As[src][(m0 + mi * 16 + la) * 72 + (ks * 4 + qg) * 8];
#pragma unroll
      for (int ni = 0; ni < 4; ++ni) {
        const int ro = o0 + ni * 16 + la;
        bfr[ni] = *(const ushort8*)&Bs[src][ro * 64 + (((ks * 4 + qg) ^ (ro & 7))) * 8];
      }
#pragma unroll
      for (int mi = 0; mi < 4; ++mi)
#pragma unroll
        for (int ni = 0; ni < 4; ++ni)
          acc[mi][ni] = mfma16(af[mi], bfr[ni], acc[mi][ni]);
    }
  };

  LOAD_A(0); STAGE_B(0, 0); PROC_A(0, 0);
  __syncthreads();
  int buf = 0;
  for (int ch = 0; ch < 6; ++ch) {
    const int nxt = ch + 1;
    if (nxt < 6) { STAGE_B(nxt, buf ^ 1); LOAD_A(nxt); }
    COMPUTE(buf);
    if (nxt < 6) PROC_A(nxt, buf ^ 1);
    __syncthreads();
    buf ^= 1;
  }

  // epilogue: y1 bf16 store
#pragma unroll
  for (int mi = 0; mi < 4; ++mi)
#pragma unroll
    for (int ni = 0; ni < 4; ++ni) {
      const int oc = o0 + ni * 16 + la;
#pragma unroll
      for (int r = 0; r < 4; ++r) {
        const int m = gm0 + m0 + mi * 16 + qg * 4 + r;
        y1[(size_t)m * 256 + oc] = f2b(acc[mi][ni][r]);
      }
    }
  // BN partial sums
#pragma unroll
  for (int ni = 0; ni < 4; ++ni) {
    float s = 0.f, qq = 0.f;
#pragma unroll
    for (int mi = 0; mi < 4; ++mi)
#pragma unroll
      for (int r = 0; r < 4; ++r) {
        const float v = acc[mi][ni][r];
        s += v; qq = fmaf(v, v, qq);
      }
    s += __shfl_xor(s, 16); s += __shfl_xor(s, 32);
    qq += __shfl_xor(qq, 16); qq += __shfl_xor(qq, 32);
    if (lane < 16) {
      sRedS[wm * 256 + o0 + ni * 16 + lane] = s;
      sRedQ[wm * 256 + o0 + ni * 16 + lane] = qq;
    }
  }
  __syncthreads();
  if (tid < 256) {
    part[(size_t)blockIdx.x * 512 + tid] = sRedS[tid] + sRedS[256 + tid];
    part[(size_t)blockIdx.x * 512 + 256 + tid] = sRedQ[tid] + sRedQ[256 + tid];
  }
}

// ---------------- reduce partials -> a,c coefficients ----------------
__global__ __launch_bounds__(1024) void k_reduce(const float* __restrict__ part, int nblk,
                                                 const float* __restrict__ g,
                                                 const float* __restrict__ be,
                                                 float* __restrict__ stats) {
  __shared__ float r0[1024];
  __shared__ float r1[1024];
  const int o = threadIdx.x & 255, q = threadIdx.x >> 8;
  float s = 0.0f, sq = 0.0f;
  for (int i = q; i < nblk; i += 4) {
    s  += part[(size_t)i * 512 + o];
    sq += part[(size_t)i * 512 + 256 + o];
  }
  r0[threadIdx.x] = s; r1[threadIdx.x] = sq;
  __syncthreads();
  if (threadIdx.x < 256) {
    s  = r0[o] + r0[256 + o] + r0[512 + o] + r0[768 + o];
    sq = r1[o] + r1[256 + o] + r1[512 + o] + r1[768 + o];
    const float mean = s * (1.0f / 65536.0f);
    float var = sq * (1.0f / 65536.0f) - mean * mean;
    var = fmaxf(var, 0.0f);
    const float inv = rsqrtf(var + 1e-3f);
    const float a = g[o] * inv;
    stats[o] = a;
    stats[256 + o] = fmaf(-mean, a, be[o]);
  }
}

// ---------------- GEMM2: y2[m][256] = relu(bn(y1)) x W2^T (in-place over y1) -------
__global__ __launch_bounds__(512, 2) void k_gemm2(
    ushort_t* y1, const ushort_t* __restrict__ Wb,
    const float* __restrict__ st1, float* __restrict__ part) {
  __shared__ __align__(16) ushort_t As[2][128 * 72];
  __shared__ __align__(16) ushort_t Bs[2][256 * 64];
  __shared__ float sSt[512];
  __shared__ float sRedS[512];
  __shared__ float sRedQ[512];

  const int tid = threadIdx.x;
  const int gm0 = blockIdx.x * 128;
  const int lane = tid & 63, wv = tid >> 6;
  const int wm = wv >> 2, wn = wv & 3;
  const int la = lane & 15, qg = lane >> 4;
  const int m0 = wm * 64, o0 = wn * 64;

  sSt[tid < 512 ? tid : 0] = st1[tid < 512 ? tid : 0];
  __syncthreads();

  const int ar = tid >> 3;
  const int ac = tid & 7;
  const int rb = ar + 64;

  f32x4 acc[4][4];
#pragma unroll
  for (int mi = 0; mi < 4; ++mi)
#pragma unroll
    for (int ni = 0; ni < 4; ++ni) acc[mi][ni] = 0.0f;

  ushort8 g0, g3;

  auto LOAD_A = [&](int ch) {
    const int ka = ch * 64 + ac * 8;
    g0 = *(const ushort8*)&y1[(size_t)(gm0 + ar) * 256 + ka];
    g3 = *(const ushort8*)&y1[(size_t)(gm0 + rb) * 256 + ka];
  };
  auto PROC_A = [&](int ch, int dst) {
    const int k0 = ch * 64 + ac * 8;
    ushort8 oa, ob;
#pragma unroll
    for (int j = 0; j < 8; ++j) {
      const float a = sSt[k0 + j], c = sSt[256 + k0 + j];
      oa[j] = f2b(fmaxf(fmaf(b2f(g0[j]), a, c), 0.0f));
      ob[j] = f2b(fmaxf(fmaf(b2f(g3[j]), a, c), 0.0f));
    }
    *(ushort8*)&As[dst][ar * 72 + ac * 8] = oa;
    *(ushort8*)&As[dst][rb * 72 + ac * 8] = ob;
  };
  auto STAGE_B = [&](int ch, int dst) {
    const int kbase = ch * 64;
#pragma unroll
    for (int i = 0; i < 4; ++i) {
      const int fc = i * 512 + tid;
      const int row = fc >> 3, p = fc & 7;
      const int c = p ^ (row & 7);
      gl_lds16(&Wb[(size_t)row * 256 + kbase + c * 8],
               &Bs[dst][i * 4096 + wv * 512]);
    }
  };
  auto COMPUTE = [&](int src) {
#pragma unroll
    for (int ks = 0; ks < 2; ++ks) {
      ushort8 af[4], bfr[4];
#pragma unroll
      for (int mi = 0; mi < 4; ++mi)
        af[mi] = *(const ushort8*)&As[src][(m0 + mi * 16 + la) * 72 + (ks * 4 + qg) * 8];
#pragma unroll
      for (int ni = 0; ni < 4; ++ni) {
        const int ro = o0 + ni * 16 + la;
        bfr[ni] = *(const ushort8*)&Bs[src][ro * 64 + (((ks * 4 + qg) ^ (ro & 7))) * 8];
      }
#pragma unroll
      for (int mi = 0; mi < 4; ++mi)
#pragma unroll
        for (int ni = 0; ni < 4; ++ni)
          acc[mi][ni] = mfma16(af[mi], bfr[ni], acc[mi][ni]);
    }
  };

  LOAD_A(0); STAGE_B(0, 0); PROC_A(0, 0);
  __syncthreads();
  int buf = 0;
  for (int ch = 0; ch < 4; ++ch) {
    const int nxt = ch + 1;
    if (nxt < 4) { STAGE_B(nxt, buf ^ 1); LOAD_A(nxt); }
    COMPUTE(buf);
    if (nxt < 4) PROC_A(nxt, buf ^ 1);
    __syncthreads();
    buf ^= 1;
  }

  // epilogue: y2 bf16 (pre-BN) in-place + partials
#pragma unroll
  for (int mi = 0; mi < 4; ++mi)
#pragma unroll
    for (int ni = 0; ni < 4; ++ni) {
      const int oc = o0 + ni * 16 + la;
#pragma unroll
      for (int r = 0; r < 4; ++r) {
        const int m = gm0 + m0 + mi * 16 + qg * 4 + r;
        y1[(size_t)m * 256 + oc] = f2b(acc[mi][ni][r]);
      }
    }
#pragma unroll
  for (int ni = 0; ni < 4; ++ni) {
    float s = 0.f, qq = 0.f;
#pragma unroll
    for (int mi = 0; mi < 4; ++mi)
#pragma unroll
      for (int r = 0; r < 4; ++r) {
        const float v = acc[mi][ni][r];
        s += v; qq = fmaf(v, v, qq);
      }
    s += __shfl_xor(s, 16); s += __shfl_xor(s, 32);
    qq += __shfl_xor(qq, 16); qq += __shfl_xor(qq, 32);
    if (lane < 16) {
      sRedS[wm * 256 + o0 + ni * 16 + lane] = s;
      sRedQ[wm * 256 + o0 + ni * 16 + lane] = qq;
    }
  }
  __syncthreads();
  if (tid < 256) {
    part[(size_t)blockIdx.x * 512 + tid] = sRedS[tid] + sRedS[256 + tid];
    part[(size_t)blockIdx.x * 512 + 256 + tid] = sRedQ[tid] + sRedQ[256 + tid];
  }
}

// ---------------- final: BN+ReLU + transpose y2[m][o] -> out[b][o][n] (f32) --------
__global__ __launch_bounds__(256) void k_final(const ushort_t* __restrict__ y2,
                                               const float* __restrict__ st2,
                                               float* __restrict__ out) {
  __shared__ __align__(16) ushort_t tile[64 * 264];
  const int t = threadIdx.x;
  const int n0 = blockIdx.x * 64;
  const int b = blockIdx.y;
#pragma unroll
  for (int r = 0; r < 8; ++r) {
    const int id = r * 256 + t;
    const int row = id >> 5, c8 = id & 31;
    *(ushort8*)&tile[row * 264 + c8 * 8] =
        *(const ushort8*)&y2[((size_t)b * N2_ + n0 + row) * 256 + c8 * 8];
  }
  __syncthreads();
#pragma unroll
  for (int r = 0; r < 16; ++r) {
    const int id = r * 256 + t;
    const int o = id >> 4, nq = id & 15;
    const float a = st2[o], c = st2[256 + o];
    float4 v;
    v.x = fmaxf(fmaf(b2f(tile[(nq * 4 + 0) * 264 + o]), a, c), 0.0f);
    v.y = fmaxf(fmaf(b2f(tile[(nq * 4 + 1) * 264 + o]), a, c), 0.0f);
    v.z = fmaxf(fmaf(b2f(tile[(nq * 4 + 2) * 264 + o]), a, c), 0.0f);
    v.w = fmaxf(fmaf(b2f(tile[(nq * 4 + 3) * 264 + o]), a, c), 0.0f);
    *(float4*)&out[((size_t)b * 256 + o) * N2_ + n0 + nq * 4] = v;
  }
}

extern "C" void kernel_launch(void* const* d_in, const int* in_sizes, int n_in,
                              void* d_out, int out_size, void* d_ws, size_t ws_size,
                              hipStream_t stream) {
  (void)in_sizes; (void)n_in; (void)out_size; (void)ws_size;
  const float* xyz2  = (const float*)d_in[0];
  const float* xyz1  = (const float*)d_in[1];
  const float* feat2 = (const float*)d_in[2];
  const float* feat1 = (const float*)d_in[3];
  const float* W1  = (const float*)d_in[4];
  const float* g1  = (const float*)d_in[6];
  const float* be1 = (const float*)d_in[7];
  const float* W2  = (const float*)d_in[8];
  const float* g2  = (const float*)d_in[10];
  const float* be2 = (const float*)d_in[11];
  float* out = (float*)d_out;

  char* ws = (char*)d_ws;
  int*      ind   = (int*)(ws);                    //   786,432
  float*    wgt   = (float*)(ws + 786432);         //   786,432
  ushort_t* f1tb  = (ushort_t*)(ws + 1572864);     // 8,388,608
  ushort_t* f2tb  = (ushort_t*)(ws + 9961472);     // 16,777,216
  ushort_t* W1b   = (ushort_t*)(ws + 26738688);    //   196,608
  ushort_t* W2b   = (ushort_t*)(ws + 26935296);    //   131,072
  float*    part1 = (float*)(ws + 27066368);       // 1,048,576
  float*    part2 = (float*)(ws + 28114944);       // 1,048,576
  float*    st1   = (float*)(ws + 29163520);       //     2,048
  float*    st2   = (float*)(ws + 29165568);       //     2,048
  ushort_t* y1    = (ushort_t*)(ws + 29167616);    // 33,554,432 (y2 in-place)

  k_three_nn<<<dim3(128, 8), 256, 0, stream>>>(xyz2, xyz1, ind, wgt);
  k_tcvt<<<dim3(64, 8, 8),  dim3(32, 8), 0, stream>>>(feat1, f1tb, 256, 2048);
  k_tcvt<<<dim3(256, 4, 8), dim3(32, 8), 0, stream>>>(feat2, f2tb, 128, 8192);
  k_wcvt<<<96, 256, 0, stream>>>(W1, W1b, 98304);
  k_wcvt<<<64, 256, 0, stream>>>(W2, W2b, 65536);
  k_gemm1<<<512, 512, 0, stream>>>(f1tb, f2tb, ind, wgt, W1b, y1, part1);
  k_reduce<<<1, 1024, 0, stream>>>(part1, 512, g1, be1, st1);
  k_gemm2<<<512, 512, 0, stream>>>(y1, W2b, st1, part2);
  k_reduce<<<1, 1024, 0, stream>>>(part2, 512, g2, be2, st2);
  k_final<<<dim3(128, 8), 256, 0, stream>>>(y1, st2, out);
}